// Round 10
// baseline (259.189 us; speedup 1.0000x reference)
//
#include <hip/hip_runtime.h>
#include <math.h>

#define NPGN 61
#define NGRAPH 128
#define NNODES (NPGN*NGRAPH)   // 7808
#define EPG 3660               // 61*60 edges per graph

typedef float float4v __attribute__((ext_vector_type(4)));
typedef short bf16x8 __attribute__((ext_vector_type(8)));
typedef unsigned short u16;

__device__ __forceinline__ u16 f2bf(float v){
  union { float f; unsigned u; } x; x.f = v;
  unsigned r = (x.u + 0x7FFFu + ((x.u >> 16) & 1u)) >> 16;
  return (u16)r;
}
__device__ __forceinline__ float bf2f(unsigned u){
  union { unsigned u; float f; } x; x.u = u << 16;
  return x.f;
}

// ---------------- fused prep: weight re-layouts + lw0 transpose -------------
// blocks [0,290): w-layouts ; [290,534): lw0t
__global__ __launch_bounds__(256) void k_prep(const float* __restrict__ w0,
    const float* __restrict__ w1, const float* __restrict__ w2,
    const float* __restrict__ gw0, const float* __restrict__ gw1, const float* __restrict__ gw2,
    const float* __restrict__ lw0,
    float* __restrict__ w0t, u16* __restrict__ w1b, u16* __restrict__ w2b,
    u16* __restrict__ gwt0, u16* __restrict__ gwt1, u16* __restrict__ gwt2,
    u16* __restrict__ lw0t){
  __shared__ __align__(16) u16 tile[32*132];
  int b = blockIdx.x, tid = threadIdx.x;
  if (b < 290){
    int idx = b*256 + tid;
    if (idx < 20480){
      int f = idx / 320, r = idx - f*320;
      int kk = r >> 6, c = r & 63;
      w1b[idx] = f2bf(w1[f*320 + c*5 + kk]);
    } else if (idx < 32768){
      int j = idx - 20480; w2b[j] = f2bf(w2[j]);
    } else if (idx < 40960){
      int j = idx - 32768; int jj = j >> 6, k = j & 63; gwt0[j] = f2bf(gw0[k*128 + jj]);
    } else if (idx < 57344){
      int j = idx - 40960; int jj = j >> 7, k = j & 127; gwt1[j] = f2bf(gw1[k*128 + jj]);
    } else if (idx < 73728){
      int j = idx - 57344; int jj = j >> 7, k = j & 127; gwt2[j] = f2bf(gw2[k*128 + jj]);
    } else if (idx < 74176){
      int j = idx - 73728; int k = j >> 6, f = j & 63; w0t[j] = w0[f*7 + k];
    }
  } else {
    int bb = b - 290;
    int i = bb >> 2, oq = bb & 3;      // o-chunk of 32
    for (int idx = tid; idx < 4096; idx += 256){
      int k = idx >> 5, ol = idx & 31;
      tile[ol*132 + k] = f2bf(lw0[((size_t)i*128 + k)*128 + oq*32 + ol]);
    }
    __syncthreads();
    unsigned* dst = (unsigned*)lw0t;
    for (int idx = tid; idx < 2048; idx += 256){
      int ol = idx >> 6, kw = idx & 63;
      unsigned v = (unsigned)tile[ol*132 + 2*kw] | ((unsigned)tile[ol*132 + 2*kw + 1] << 16);
      dst[((size_t)i*128 + oq*32 + ol)*64 + kw] = v;
    }
  }
}

// ---------------- fused conv stack (R5 structure) + bn1-stats tail ----------
// 4 independent waves/block, 1 node/wave; conv0 scalar-VALU, conv1/conv2 MFMA
#define A0T_STR 72   // u16 units (144 B)
#define C1_STR 40    // u16 units (80 B)
__global__ __launch_bounds__(256) void k_conv(const float* __restrict__ x,
    const float* __restrict__ w0t, const float* __restrict__ b0,
    const u16* __restrict__ w1b, const float* __restrict__ b1,
    const u16* __restrict__ w2b, const float* __restrict__ b2,
    float* __restrict__ h0, float* __restrict__ stat1acc){
  int w = threadIdx.x >> 6, lane = threadIdx.x & 63;
  int tid = threadIdx.x;
  int n = blockIdx.x*4 + w;
  __shared__ __align__(16) u16 a0t_s[4][36*A0T_STR];  // 5184 B/wave; c1 overlays
  __shared__ __align__(16) u16 a1k_s[4][208];         // conv2 input vector
  __shared__ float hstat[4][128];
  u16* a0t = a0t_s[w];
  u16* a1k = a1k_s[w];

  // wave-uniform x row -> scalar loads
  const float* xrow = x + (size_t)__builtin_amdgcn_readfirstlane(n)*160;

  float w0r[7];
  #pragma unroll
  for (int k = 0; k < 7; k++) w0r[k] = w0t[k*64 + lane];
  float b0f = b0[lane];
  #pragma unroll
  for (int rp = 0; rp < 36; rp++)
    if (rp < 2 || rp >= 24) a0t[rp*A0T_STR + lane] = 0;

  // conv0 (K=7) + relu + maxpool7 : 160 -> 154 -> 22 ; lane = channel
  #pragma unroll 2
  for (int qp = 0; qp < 11; qp++){
    float win[20];
    #pragma unroll
    for (int j = 0; j < 20; j++) win[j] = xrow[14*qp + j];
    float m0, m1;
    #pragma unroll
    for (int r = 0; r < 7; r++){
      float s = w0r[0]*win[r];
      #pragma unroll
      for (int k = 1; k < 7; k++) s += w0r[k]*win[r+k];
      m0 = r ? fmaxf(m0, s) : s;
    }
    #pragma unroll
    for (int r = 7; r < 14; r++){
      float s = w0r[0]*win[r];
      #pragma unroll
      for (int k = 1; k < 7; k++) s += w0r[k]*win[r+k];
      m1 = (r > 7) ? fmaxf(m1, s) : s;
    }
    a0t[(2 + 2*qp)*A0T_STR + lane] = f2bf(fmaxf(m0 + b0f, 0.f));
    a0t[(3 + 2*qp)*A0T_STR + lane] = f2bf(fmaxf(m1 + b0f, 0.f));
  }

  // conv1 MFMA: C[64f][22p] = W[64f][320] * B[320][22p], k = kk*64 + c
  int q = lane >> 4, r16 = lane & 15;
  float4v acc[4][2];
  #pragma unroll
  for (int mt = 0; mt < 4; mt++)
    #pragma unroll
    for (int nt = 0; nt < 2; nt++)
      acc[mt][nt] = (float4v){0.f,0.f,0.f,0.f};
  #pragma unroll 1
  for (int ks = 0; ks < 10; ks++){
    int kk = ks >> 1;
    int cbase = (ks & 1)*32 + q*8;
    bf16x8 af[4];
    #pragma unroll
    for (int mt = 0; mt < 4; mt++)
      af[mt] = *(const bf16x8*)(w1b + (16*mt + r16)*320 + ks*32 + q*8);
    bf16x8 bv[2];
    #pragma unroll
    for (int nt = 0; nt < 2; nt++)
      bv[nt] = *(const bf16x8*)(a0t + (r16 + 16*nt + kk)*A0T_STR + cbase);
    #pragma unroll
    for (int mt = 0; mt < 4; mt++)
      #pragma unroll
      for (int nt = 0; nt < 2; nt++)
        acc[mt][nt] = __builtin_amdgcn_mfma_f32_16x16x32_bf16(af[mt], bv[nt], acc[mt][nt], 0, 0, 0);
  }

  // bias + relu -> c1 (bf16, overlays a0t; same-wave DS ops in-order)
  u16* c1 = a0t;
  #pragma unroll
  for (int mt = 0; mt < 4; mt++){
    float4 bb = *(const float4*)(b1 + 16*mt + 4*q);
    #pragma unroll
    for (int reg = 0; reg < 4; reg++){
      int m = 16*mt + q*4 + reg;
      float bv_ = ((const float*)&bb)[reg];
      c1[m*C1_STR + r16] = f2bf(fmaxf(acc[mt][0][reg] + bv_, 0.f));
      if (r16 <= 4)
        c1[m*C1_STR + 16 + r16] = f2bf(fmaxf(acc[mt][1][reg] + bv_, 0.f));
    }
  }

  // maxpool7 (21 -> 3), lane = channel; contiguous k-vector a1k[c*3+t]
  {
    bf16x8 f0 = *(const bf16x8*)(c1 + lane*C1_STR);
    bf16x8 f1 = *(const bf16x8*)(c1 + lane*C1_STR + 8);
    bf16x8 f2 = *(const bf16x8*)(c1 + lane*C1_STR + 16);
    float v[24];
    #pragma unroll
    for (int j = 0; j < 8; j++){
      v[j]    = bf2f((u16)f0[j]);
      v[8+j]  = bf2f((u16)f1[j]);
      v[16+j] = bf2f((u16)f2[j]);
    }
    #pragma unroll
    for (int t = 0; t < 3; t++){
      float m = v[t*7];
      #pragma unroll
      for (int r = 1; r < 7; r++) m = fmaxf(m, v[t*7+r]);
      a1k[lane*3 + t] = f2bf(m);
    }
  }

  // conv2 via MFMA: C[f][*] = W2[64f][192k] * a1[192k]
  float4v acc2[4];
  #pragma unroll
  for (int mt = 0; mt < 4; mt++) acc2[mt] = (float4v){0.f,0.f,0.f,0.f};
  #pragma unroll
  for (int ks = 0; ks < 6; ks++){
    bf16x8 bs = *(const bf16x8*)(a1k + ks*32 + q*8);
    #pragma unroll
    for (int mt = 0; mt < 4; mt++){
      bf16x8 af = *(const bf16x8*)(w2b + (16*mt + r16)*192 + ks*32 + q*8);
      acc2[mt] = __builtin_amdgcn_mfma_f32_16x16x32_bf16(af, bs, acc2[mt], 0, 0, 0);
    }
  }
  if (r16 == 0){
    #pragma unroll
    for (int mt = 0; mt < 4; mt++)
      #pragma unroll
      for (int reg = 0; reg < 4; reg++){
        int f = 16*mt + 4*q + reg;
        float v = acc2[mt][reg] + b2[f];
        h0[(size_t)n*64 + f] = v;
        hstat[w][f] = v;
        hstat[w][64 + f] = v*v;
      }
  }
  __syncthreads();
  // per-block bn1 partial (4 nodes) -> global atomic accumulators
  if (tid < 128){
    float a = hstat[0][tid] + hstat[1][tid] + hstat[2][tid] + hstat[3][tid];
    atomicAdd(&stat1acc[tid], a);
  }
}

// ---------------- fused GNN: edge-tanh head + 3 MFMA layers + bn2-stats tail
#define EW_STR 72
#define HS_STR 136
#define HWT_STR 72
__global__ __launch_bounds__(512) void k_gnn(const float* __restrict__ h0,
    const float* __restrict__ stat1acc,
    const float* __restrict__ bn1g, const float* __restrict__ bn1b,
    const u16* __restrict__ gwt0, const float* __restrict__ gb0,
    const u16* __restrict__ gwt1, const float* __restrict__ gb1,
    const u16* __restrict__ gwt2, const float* __restrict__ gb2,
    const float* __restrict__ ef, const float* __restrict__ eww,
    const float* __restrict__ ewb, float* __restrict__ out2,
    u16* __restrict__ hB, float* __restrict__ stat2acc){
  int g = blockIdx.x, tid = threadIdx.x;
  int w = tid >> 6, lane = tid & 63, q = lane >> 4, r16 = lane & 15;
  int dt = w & 3, jh = w >> 2;
  __shared__ u16 hs[64*HS_STR];
  __shared__ u16 hwT[128*HWT_STR];
  __shared__ u16 ewl[64*EW_STR];
  __shared__ float bsc[64], bsh[64];
  __shared__ float st2[256];

  bf16x8 af0[2], af1[4], af2[4];
  #pragma unroll
  for (int ks = 0; ks < 2; ks++)
    af0[ks] = *(const bf16x8*)(gwt0 + (16*w + r16)*64 + ks*32 + q*8);
  #pragma unroll
  for (int ks = 0; ks < 4; ks++)
    af1[ks] = *(const bf16x8*)(gwt1 + (16*w + r16)*128 + ks*32 + q*8);
  #pragma unroll
  for (int ks = 0; ks < 4; ks++)
    af2[ks] = *(const bf16x8*)(gwt2 + (16*w + r16)*128 + ks*32 + q*8);
  float4 b40 = *(const float4*)(gb0 + 16*w + 4*q);
  float4 b41 = *(const float4*)(gb1 + 16*w + 4*q);
  float4 b42 = *(const float4*)(gb2 + 16*w + 4*q);

  // bn1 scale/shift from global accumulators
  if (tid < 64){
    float s = stat1acc[tid], s2 = stat1acc[64 + tid];
    float m = s*(1.f/NNODES), v = s2*(1.f/NNODES) - m*m;
    float sc = rsqrtf(v + 1e-5f)*bn1g[tid];
    bsc[tid] = sc; bsh[tid] = bn1b[tid] - m*sc;
  }
  if (tid < 256) st2[tid] = 0.f;
  {
    unsigned* td = (unsigned*)ewl;
    for (int idx = tid; idx < 64*EW_STR/2; idx += 512) td[idx] = 0;
  }
  {
    unsigned* hsd = (unsigned*)hs;
    for (int idx = tid; idx < 3*(HS_STR/2); idx += 512){
      int rr = 61 + idx/(HS_STR/2), cc = idx%(HS_STR/2);
      hsd[rr*(HS_STR/2) + cc] = 0;
    }
  }
  __syncthreads();

  // edge tanh -> dense LDS matrix + transposed global output
  {
    float v0 = eww[0], v1 = eww[1], v2 = eww[2], bb = ewb[0];
    const float* efg = ef + (size_t)g*EPG*3;
    for (int idx = tid; idx < EPG; idx += 512){
      const float* p = efg + idx*3;
      float v = tanhf(p[0]*v0 + p[1]*v1 + p[2]*v2 + bb);
      int s = idx/60, r = idx - s*60;
      int d = r + (r >= s ? 1 : 0);
      ewl[d*EW_STR + s] = f2bf(v);
      out2[(size_t)idx*128 + g] = v;
    }
  }
  // bn1-normalized node features -> hs
  {
    unsigned* hsd = (unsigned*)hs;
    for (int idx = tid; idx < 61*32; idx += 512){
      int i = idx >> 5, kw = idx & 31;
      float2 hv = *(const float2*)(h0 + ((size_t)g*61 + i)*64 + kw*2);
      int k0 = kw*2;
      float a = hv.x*bsc[k0] + bsh[k0];
      float b = hv.y*bsc[k0+1] + bsh[k0+1];
      hsd[i*(HS_STR/2) + kw] = (unsigned)f2bf(a) | ((unsigned)f2bf(b) << 16);
    }
  }
  __syncthreads();
  bf16x8 ewf[2];
  #pragma unroll
  for (int ks = 0; ks < 2; ks++)
    ewf[ks] = *(const bf16x8*)(ewl + (16*dt + r16)*EW_STR + ks*32 + q*8);

  // layer 0
  #pragma unroll
  for (int nt = 0; nt < 4; nt++){
    float4v acc = {b40.x, b40.y, b40.z, b40.w};
    #pragma unroll
    for (int ks = 0; ks < 2; ks++){
      bf16x8 bv = *(const bf16x8*)(hs + (nt*16 + r16)*HS_STR + ks*32 + q*8);
      acc = __builtin_amdgcn_mfma_f32_16x16x32_bf16(af0[ks], bv, acc, 0, 0, 0);
    }
    #pragma unroll
    for (int r = 0; r < 4; r++)
      hwT[(16*w + 4*q + r)*HWT_STR + nt*16 + r16] = f2bf(acc[r]);
  }
  __syncthreads();
  #pragma unroll
  for (int nt = 0; nt < 4; nt++){
    int j = (jh*4 + nt)*16;
    float4v acc = {0.f,0.f,0.f,0.f};
    #pragma unroll
    for (int ks = 0; ks < 2; ks++){
      bf16x8 bv = *(const bf16x8*)(hwT + (j + r16)*HWT_STR + ks*32 + q*8);
      acc = __builtin_amdgcn_mfma_f32_16x16x32_bf16(ewf[ks], bv, acc, 0, 0, 0);
    }
    #pragma unroll
    for (int r = 0; r < 4; r++){
      int d = 16*dt + 4*q + r;
      hs[d*HS_STR + j + r16] = f2bf(fmaxf(acc[r], 0.f));
    }
  }
  __syncthreads();

  // layer 1
  #pragma unroll
  for (int nt = 0; nt < 4; nt++){
    float4v acc = {b41.x, b41.y, b41.z, b41.w};
    #pragma unroll
    for (int ks = 0; ks < 4; ks++){
      bf16x8 bv = *(const bf16x8*)(hs + (nt*16 + r16)*HS_STR + ks*32 + q*8);
      acc = __builtin_amdgcn_mfma_f32_16x16x32_bf16(af1[ks], bv, acc, 0, 0, 0);
    }
    #pragma unroll
    for (int r = 0; r < 4; r++)
      hwT[(16*w + 4*q + r)*HWT_STR + nt*16 + r16] = f2bf(acc[r]);
  }
  __syncthreads();
  #pragma unroll
  for (int nt = 0; nt < 4; nt++){
    int j = (jh*4 + nt)*16;
    float4v acc = {0.f,0.f,0.f,0.f};
    #pragma unroll
    for (int ks = 0; ks < 2; ks++){
      bf16x8 bv = *(const bf16x8*)(hwT + (j + r16)*HWT_STR + ks*32 + q*8);
      acc = __builtin_amdgcn_mfma_f32_16x16x32_bf16(ewf[ks], bv, acc, 0, 0, 0);
    }
    #pragma unroll
    for (int r = 0; r < 4; r++){
      int d = 16*dt + 4*q + r;
      hs[d*HS_STR + j + r16] = f2bf(fmaxf(acc[r], 0.f));
    }
  }
  __syncthreads();

  // layer 2 (+ bn2 stats tail)
  #pragma unroll
  for (int nt = 0; nt < 4; nt++){
    float4v acc = {b42.x, b42.y, b42.z, b42.w};
    #pragma unroll
    for (int ks = 0; ks < 4; ks++){
      bf16x8 bv = *(const bf16x8*)(hs + (nt*16 + r16)*HS_STR + ks*32 + q*8);
      acc = __builtin_amdgcn_mfma_f32_16x16x32_bf16(af2[ks], bv, acc, 0, 0, 0);
    }
    #pragma unroll
    for (int r = 0; r < 4; r++)
      hwT[(16*w + 4*q + r)*HWT_STR + nt*16 + r16] = f2bf(acc[r]);
  }
  __syncthreads();
  #pragma unroll
  for (int nt = 0; nt < 4; nt++){
    int j = (jh*4 + nt)*16;
    float4v acc = {0.f,0.f,0.f,0.f};
    #pragma unroll
    for (int ks = 0; ks < 2; ks++){
      bf16x8 bv = *(const bf16x8*)(hwT + (j + r16)*HWT_STR + ks*32 + q*8);
      acc = __builtin_amdgcn_mfma_f32_16x16x32_bf16(ewf[ks], bv, acc, 0, 0, 0);
    }
    float cs = 0.f, cq = 0.f;
    #pragma unroll
    for (int r = 0; r < 4; r++){
      int d = 16*dt + 4*q + r;
      if (d < 61){
        float v = acc[r];
        hB[((size_t)g*61 + d)*128 + j + r16] = f2bf(v);
        cs += v; cq += v*v;
      }
    }
    int col = j + r16;
    atomicAdd(&st2[col], cs);
    atomicAdd(&st2[128 + col], cq);
  }
  __syncthreads();
  if (tid < 256) atomicAdd(&stat2acc[tid], st2[tid]);
}

// ---------------- lin0 via MFMA, atomic split-K into y0pre ------------------
#define AS_STR 136
__global__ __launch_bounds__(256) void k_mlp0(const u16* __restrict__ hB,
    const float* __restrict__ stat2acc,
    const float* __restrict__ bn2g, const float* __restrict__ bn2b,
    const u16* __restrict__ lw0t, float* __restrict__ y0pre){
  int bi = blockIdx.x; int i = bi >> 2, sub = bi & 3;
  int oh = sub & 1, gh = sub >> 1;
  int tid = threadIdx.x, w = tid >> 6, lane = tid & 63, q = lane >> 4, r16 = lane & 15;
  __shared__ u16 As[64*AS_STR];
  __shared__ float sc2[128], sh2[128];
  if (tid < 128){
    float s = stat2acc[tid], s2 = stat2acc[128 + tid];
    float m = s*(1.f/NNODES), v = s2*(1.f/NNODES) - m*m;
    float sc = rsqrtf(v + 1e-5f)*bn2g[tid];
    sc2[tid] = sc; sh2[tid] = bn2b[tid] - m*sc;
  }
  __syncthreads();
  {
    const unsigned* hbd = (const unsigned*)hB;
    unsigned* asd = (unsigned*)As;
    for (int idx = tid; idx < 4096; idx += 256){
      int gg = gh*64 + (idx >> 6), kw = idx & 63;
      unsigned pv = hbd[((size_t)gg*61 + i)*64 + kw];
      int k0 = kw*2;
      float a = bf2f(pv & 0xffffu)*sc2[k0] + sh2[k0];
      float b = bf2f(pv >> 16)*sc2[k0+1] + sh2[k0+1];
      asd[(idx >> 6)*(AS_STR/2) + kw] = (unsigned)f2bf(a) | ((unsigned)f2bf(b) << 16);
    }
  }
  __syncthreads();
  const u16* wbase = lw0t + ((size_t)i*128 + oh*64)*128;
  bf16x8 af[4];
  #pragma unroll
  for (int ks = 0; ks < 4; ks++)
    af[ks] = *(const bf16x8*)(As + (16*w + r16)*AS_STR + ks*32 + q*8);
  #pragma unroll 1
  for (int nt = 0; nt < 4; nt++){
    float4v acc = {0.f,0.f,0.f,0.f};
    #pragma unroll
    for (int ks = 0; ks < 4; ks++){
      bf16x8 bv = *(const bf16x8*)(wbase + (size_t)(nt*16 + r16)*128 + ks*32 + q*8);
      acc = __builtin_amdgcn_mfma_f32_16x16x32_bf16(af[ks], bv, acc, 0, 0, 0);
    }
    #pragma unroll
    for (int r = 0; r < 4; r++){
      int g = gh*64 + 16*w + 4*q + r;
      atomicAdd(&y0pre[(size_t)g*128 + oh*64 + nt*16 + r16], acc[r]);
    }
  }
}

// ---------------- epilogue: bias+relu + lin1 + lin2 + log_softmax -----------
__global__ __launch_bounds__(128) void k_mlp1(const float* __restrict__ y0pre,
    const float* __restrict__ lb0, const float* __restrict__ W1,
    const float* __restrict__ lb1, const float* __restrict__ W2,
    const float* __restrict__ lb2, float* __restrict__ out){
  int g = blockIdx.x, o = threadIdx.x;
  __shared__ float y0[128], y1[128], red[128];
  y0[o] = fmaxf(y0pre[(size_t)g*128 + o] + lb0[o], 0.f);
  __syncthreads();
  float a = lb1[o];
  #pragma unroll 1
  for (int k = 0; k < 128; k++) a += y0[k]*W1[k*128 + o];
  y1[o] = fmaxf(a, 0.f);
  __syncthreads();
  int c = o & 3, kb = o >> 2;
  float a2 = 0.f;
  #pragma unroll
  for (int j = 0; j < 4; j++){
    int k = kb + 32*j;
    a2 += y1[k]*W2[k*4 + c];
  }
  red[o] = a2;
  __syncthreads();
  #pragma unroll
  for (int off = 64; off >= 4; off >>= 1){
    if (o < off) red[o] += red[o + off];
    __syncthreads();
  }
  if (o == 0){
    float v0 = red[0]+lb2[0], v1 = red[1]+lb2[1], v2 = red[2]+lb2[2], v3 = red[3]+lb2[3];
    float m = fmaxf(fmaxf(v0,v1), fmaxf(v2,v3));
    float lse = m + logf(expf(v0-m)+expf(v1-m)+expf(v2-m)+expf(v3-m));
    out[g*4+0]=v0-lse; out[g*4+1]=v1-lse; out[g*4+2]=v2-lse; out[g*4+3]=v3-lse;
  }
}

extern "C" void kernel_launch(void* const* d_in, const int* in_sizes, int n_in,
                              void* d_out, int out_size, void* d_ws, size_t ws_size,
                              hipStream_t stream){
  const float* x    = (const float*)d_in[0];
  const float* ef   = (const float*)d_in[3];
  const float* cw0  = (const float*)d_in[4];
  const float* cb0  = (const float*)d_in[5];
  const float* cw1  = (const float*)d_in[6];
  const float* cb1  = (const float*)d_in[7];
  const float* cw2  = (const float*)d_in[8];
  const float* cb2  = (const float*)d_in[9];
  const float* bn1g = (const float*)d_in[10];
  const float* bn1b = (const float*)d_in[11];
  const float* gw0  = (const float*)d_in[12];
  const float* gb0  = (const float*)d_in[13];
  const float* gw1  = (const float*)d_in[14];
  const float* gb1  = (const float*)d_in[15];
  const float* gw2  = (const float*)d_in[16];
  const float* gb2  = (const float*)d_in[17];
  const float* bn2g = (const float*)d_in[18];
  const float* bn2b = (const float*)d_in[19];
  const float* lw0  = (const float*)d_in[20];
  const float* lb0  = (const float*)d_in[21];
  const float* lw1  = (const float*)d_in[22];
  const float* lb1  = (const float*)d_in[23];
  const float* lw2  = (const float*)d_in[24];
  const float* lb2  = (const float*)d_in[25];
  const float* eww  = (const float*)d_in[26];
  const float* ewb  = (const float*)d_in[27];
  float* out = (float*)d_out;

  float* ws   = (float*)d_ws;
  float* w1s  = ws;               // 10240 f
  float* w2s  = w1s + 10240;      // 6144 f
  float* w0t  = w2s + 6144;       // 448 f
  float* gws0 = w0t + 448;        // 4096 f
  float* gws1 = gws0 + 4096;      // 8192 f
  float* gws2 = gws1 + 8192;      // 8192 f
  float* h0   = gws2 + 8192;      // 499712 f (7808*64 f32)
  float* hBs  = h0 + 499712;      // 499712 f (7808*128 u16)
  float* lw0s = hBs + 499712;     // 499712 f (61*128*128 u16)
  float* accs = lw0s + 499712;    // 16768 f: stat1acc(128) | stat2acc(256) | y0pre(16384)
  // total ~ 6.2 MB

  u16* w1b    = (u16*)w1s;
  u16* w2b    = (u16*)w2s;
  u16* gwt0   = (u16*)gws0;
  u16* gwt1   = (u16*)gws1;
  u16* gwt2   = (u16*)gws2;
  u16* hB     = (u16*)hBs;
  u16* lw0t   = (u16*)lw0s;
  float* stat1acc = accs;
  float* stat2acc = accs + 128;
  float* y0pre    = accs + 384;

  hipMemsetAsync(accs, 0, 16768*sizeof(float), stream);
  k_prep <<<534, 256, 0, stream>>>(cw0, cw1, cw2, gw0, gw1, gw2, lw0,
                                   w0t, w1b, w2b, gwt0, gwt1, gwt2, lw0t);
  k_conv <<<NNODES/4, 256, 0, stream>>>(x, w0t, cb0, w1b, cb1, w2b, cb2, h0, stat1acc);
  k_gnn  <<<NGRAPH, 512, 0, stream>>>(h0, stat1acc, bn1g, bn1b,
                                      gwt0, gb0, gwt1, gb1, gwt2, gb2,
                                      ef, eww, ewb, out + 512, hB, stat2acc);
  k_mlp0 <<<NPGN*4, 256, 0, stream>>>(hB, stat2acc, bn2g, bn2b, lw0t, y0pre);
  k_mlp1 <<<NGRAPH, 128, 0, stream>>>(y0pre, lb0, lw1, lb1, lw2, lb2, out);
}

// Round 11
// 240.927 us; speedup vs baseline: 1.0758x; 1.0758x over previous
//
#include <hip/hip_runtime.h>
#include <math.h>

#define NPGN 61
#define NGRAPH 128
#define NNODES (NPGN*NGRAPH)   // 7808
#define EPG 3660               // 61*60 edges per graph

typedef float float4v __attribute__((ext_vector_type(4)));
typedef short bf16x8 __attribute__((ext_vector_type(8)));
typedef unsigned short u16;

__device__ __forceinline__ u16 f2bf(float v){
  union { float f; unsigned u; } x; x.f = v;
  unsigned r = (x.u + 0x7FFFu + ((x.u >> 16) & 1u)) >> 16;
  return (u16)r;
}
__device__ __forceinline__ float bf2f(unsigned u){
  union { unsigned u; float f; } x; x.u = u << 16;
  return x.f;
}

// ---------------- fused prep: weight re-layouts + lw0 transpose -------------
// blocks [0,290): w-layouts ; [290,534): lw0t
__global__ __launch_bounds__(256) void k_prep(const float* __restrict__ w0,
    const float* __restrict__ w1, const float* __restrict__ w2,
    const float* __restrict__ gw0, const float* __restrict__ gw1, const float* __restrict__ gw2,
    const float* __restrict__ lw0,
    float* __restrict__ w0t, u16* __restrict__ w1b, u16* __restrict__ w2b,
    u16* __restrict__ gwt0, u16* __restrict__ gwt1, u16* __restrict__ gwt2,
    u16* __restrict__ lw0t){
  __shared__ __align__(16) u16 tile[32*132];
  int b = blockIdx.x, tid = threadIdx.x;
  if (b < 290){
    int idx = b*256 + tid;
    if (idx < 20480){
      int f = idx / 320, r = idx - f*320;
      int kk = r >> 6, c = r & 63;
      w1b[idx] = f2bf(w1[f*320 + c*5 + kk]);
    } else if (idx < 32768){
      int j = idx - 20480; w2b[j] = f2bf(w2[j]);
    } else if (idx < 40960){
      int j = idx - 32768; int jj = j >> 6, k = j & 63; gwt0[j] = f2bf(gw0[k*128 + jj]);
    } else if (idx < 57344){
      int j = idx - 40960; int jj = j >> 7, k = j & 127; gwt1[j] = f2bf(gw1[k*128 + jj]);
    } else if (idx < 73728){
      int j = idx - 57344; int jj = j >> 7, k = j & 127; gwt2[j] = f2bf(gw2[k*128 + jj]);
    } else if (idx < 74176){
      int j = idx - 73728; int k = j >> 6, f = j & 63; w0t[j] = w0[f*7 + k];
    }
  } else {
    int bb = b - 290;
    int i = bb >> 2, oq = bb & 3;      // o-chunk of 32
    for (int idx = tid; idx < 4096; idx += 256){
      int k = idx >> 5, ol = idx & 31;
      tile[ol*132 + k] = f2bf(lw0[((size_t)i*128 + k)*128 + oq*32 + ol]);
    }
    __syncthreads();
    unsigned* dst = (unsigned*)lw0t;
    for (int idx = tid; idx < 2048; idx += 256){
      int ol = idx >> 6, kw = idx & 63;
      unsigned v = (unsigned)tile[ol*132 + 2*kw] | ((unsigned)tile[ol*132 + 2*kw + 1] << 16);
      dst[((size_t)i*128 + oq*32 + ol)*64 + kw] = v;
    }
  }
}

// ---------------- fused conv stack + bn1-stats tail -------------------------
// 4 independent waves/block, 1 node/wave; conv0 scalar-VALU, conv1/conv2 MFMA
// conv1 K-loop: explicit distance-1 prefetch of A-fragments (L2 latency hiding)
#define A0T_STR 72   // u16 units (144 B)
#define C1_STR 40    // u16 units (80 B)
__global__ __launch_bounds__(256) void k_conv(const float* __restrict__ x,
    const float* __restrict__ w0t, const float* __restrict__ b0,
    const u16* __restrict__ w1b, const float* __restrict__ b1,
    const u16* __restrict__ w2b, const float* __restrict__ b2,
    float* __restrict__ h0, float* __restrict__ stat1acc){
  int w = threadIdx.x >> 6, lane = threadIdx.x & 63;
  int tid = threadIdx.x;
  int n = blockIdx.x*4 + w;
  __shared__ __align__(16) u16 a0t_s[4][36*A0T_STR];  // 5184 B/wave; c1 overlays
  __shared__ __align__(16) u16 a1k_s[4][208];         // conv2 input vector
  __shared__ float hstat[4][128];
  u16* a0t = a0t_s[w];
  u16* a1k = a1k_s[w];

  // wave-uniform x row -> scalar loads
  const float* xrow = x + (size_t)__builtin_amdgcn_readfirstlane(n)*160;

  float w0r[7];
  #pragma unroll
  for (int k = 0; k < 7; k++) w0r[k] = w0t[k*64 + lane];
  float b0f = b0[lane];
  #pragma unroll
  for (int rp = 0; rp < 36; rp++)
    if (rp < 2 || rp >= 24) a0t[rp*A0T_STR + lane] = 0;

  // conv0 (K=7) + relu + maxpool7 : 160 -> 154 -> 22 ; lane = channel
  #pragma unroll 2
  for (int qp = 0; qp < 11; qp++){
    float win[20];
    #pragma unroll
    for (int j = 0; j < 20; j++) win[j] = xrow[14*qp + j];
    float m0, m1;
    #pragma unroll
    for (int r = 0; r < 7; r++){
      float s = w0r[0]*win[r];
      #pragma unroll
      for (int k = 1; k < 7; k++) s += w0r[k]*win[r+k];
      m0 = r ? fmaxf(m0, s) : s;
    }
    #pragma unroll
    for (int r = 7; r < 14; r++){
      float s = w0r[0]*win[r];
      #pragma unroll
      for (int k = 1; k < 7; k++) s += w0r[k]*win[r+k];
      m1 = (r > 7) ? fmaxf(m1, s) : s;
    }
    a0t[(2 + 2*qp)*A0T_STR + lane] = f2bf(fmaxf(m0 + b0f, 0.f));
    a0t[(3 + 2*qp)*A0T_STR + lane] = f2bf(fmaxf(m1 + b0f, 0.f));
  }

  // conv1 MFMA: C[64f][22p] = W[64f][320] * B[320][22p], k = kk*64 + c
  // software-pipelined: af for ks+1 issued before ks's MFMAs
  int q = lane >> 4, r16 = lane & 15;
  float4v acc[4][2];
  #pragma unroll
  for (int mt = 0; mt < 4; mt++)
    #pragma unroll
    for (int nt = 0; nt < 2; nt++)
      acc[mt][nt] = (float4v){0.f,0.f,0.f,0.f};
  bf16x8 afc[4];
  #pragma unroll
  for (int mt = 0; mt < 4; mt++)
    afc[mt] = *(const bf16x8*)(w1b + (16*mt + r16)*320 + q*8);
  #pragma unroll 1
  for (int ks = 0; ks < 10; ks++){
    int kk = ks >> 1;
    int cbase = (ks & 1)*32 + q*8;
    bf16x8 afn[4];
    if (ks < 9){
      #pragma unroll
      for (int mt = 0; mt < 4; mt++)
        afn[mt] = *(const bf16x8*)(w1b + (16*mt + r16)*320 + (ks+1)*32 + q*8);
    }
    bf16x8 bv[2];
    #pragma unroll
    for (int nt = 0; nt < 2; nt++)
      bv[nt] = *(const bf16x8*)(a0t + (r16 + 16*nt + kk)*A0T_STR + cbase);
    #pragma unroll
    for (int mt = 0; mt < 4; mt++)
      #pragma unroll
      for (int nt = 0; nt < 2; nt++)
        acc[mt][nt] = __builtin_amdgcn_mfma_f32_16x16x32_bf16(afc[mt], bv[nt], acc[mt][nt], 0, 0, 0);
    #pragma unroll
    for (int mt = 0; mt < 4; mt++) afc[mt] = afn[mt];
  }

  // bias + relu -> c1 (bf16, overlays a0t; same-wave DS ops in-order)
  u16* c1 = a0t;
  #pragma unroll
  for (int mt = 0; mt < 4; mt++){
    float4 bb = *(const float4*)(b1 + 16*mt + 4*q);
    #pragma unroll
    for (int reg = 0; reg < 4; reg++){
      int m = 16*mt + q*4 + reg;
      float bv_ = ((const float*)&bb)[reg];
      c1[m*C1_STR + r16] = f2bf(fmaxf(acc[mt][0][reg] + bv_, 0.f));
      if (r16 <= 4)
        c1[m*C1_STR + 16 + r16] = f2bf(fmaxf(acc[mt][1][reg] + bv_, 0.f));
    }
  }

  // maxpool7 (21 -> 3), lane = channel; contiguous k-vector a1k[c*3+t]
  {
    bf16x8 f0 = *(const bf16x8*)(c1 + lane*C1_STR);
    bf16x8 f1 = *(const bf16x8*)(c1 + lane*C1_STR + 8);
    bf16x8 f2 = *(const bf16x8*)(c1 + lane*C1_STR + 16);
    float v[24];
    #pragma unroll
    for (int j = 0; j < 8; j++){
      v[j]    = bf2f((u16)f0[j]);
      v[8+j]  = bf2f((u16)f1[j]);
      v[16+j] = bf2f((u16)f2[j]);
    }
    #pragma unroll
    for (int t = 0; t < 3; t++){
      float m = v[t*7];
      #pragma unroll
      for (int r = 1; r < 7; r++) m = fmaxf(m, v[t*7+r]);
      a1k[lane*3 + t] = f2bf(m);
    }
  }

  // conv2 via MFMA: C[f][*] = W2[64f][192k] * a1[192k]  (fully unrolled: loads batch)
  float4v acc2[4];
  #pragma unroll
  for (int mt = 0; mt < 4; mt++) acc2[mt] = (float4v){0.f,0.f,0.f,0.f};
  #pragma unroll
  for (int ks = 0; ks < 6; ks++){
    bf16x8 bs = *(const bf16x8*)(a1k + ks*32 + q*8);
    #pragma unroll
    for (int mt = 0; mt < 4; mt++){
      bf16x8 af = *(const bf16x8*)(w2b + (16*mt + r16)*192 + ks*32 + q*8);
      acc2[mt] = __builtin_amdgcn_mfma_f32_16x16x32_bf16(af, bs, acc2[mt], 0, 0, 0);
    }
  }
  if (r16 == 0){
    #pragma unroll
    for (int mt = 0; mt < 4; mt++)
      #pragma unroll
      for (int reg = 0; reg < 4; reg++){
        int f = 16*mt + 4*q + reg;
        float v = acc2[mt][reg] + b2[f];
        h0[(size_t)n*64 + f] = v;
        hstat[w][f] = v;
        hstat[w][64 + f] = v*v;
      }
  }
  __syncthreads();
  // per-block bn1 partial (4 nodes) -> global atomic accumulators
  if (tid < 128){
    float a = hstat[0][tid] + hstat[1][tid] + hstat[2][tid] + hstat[3][tid];
    atomicAdd(&stat1acc[tid], a);
  }
}

// ---------------- fused GNN: edge-tanh head + 3 MFMA layers + bn2-stats tail
#define EW_STR 72
#define HS_STR 136
#define HWT_STR 72
__global__ __launch_bounds__(512) void k_gnn(const float* __restrict__ h0,
    const float* __restrict__ stat1acc,
    const float* __restrict__ bn1g, const float* __restrict__ bn1b,
    const u16* __restrict__ gwt0, const float* __restrict__ gb0,
    const u16* __restrict__ gwt1, const float* __restrict__ gb1,
    const u16* __restrict__ gwt2, const float* __restrict__ gb2,
    const float* __restrict__ ef, const float* __restrict__ eww,
    const float* __restrict__ ewb, float* __restrict__ out2,
    u16* __restrict__ hB, float* __restrict__ stat2acc){
  int g = blockIdx.x, tid = threadIdx.x;
  int w = tid >> 6, lane = tid & 63, q = lane >> 4, r16 = lane & 15;
  int dt = w & 3, jh = w >> 2;
  __shared__ u16 hs[64*HS_STR];
  __shared__ u16 hwT[128*HWT_STR];
  __shared__ u16 ewl[64*EW_STR];
  __shared__ float bsc[64], bsh[64];
  __shared__ float st2[256];

  bf16x8 af0[2], af1[4], af2[4];
  #pragma unroll
  for (int ks = 0; ks < 2; ks++)
    af0[ks] = *(const bf16x8*)(gwt0 + (16*w + r16)*64 + ks*32 + q*8);
  #pragma unroll
  for (int ks = 0; ks < 4; ks++)
    af1[ks] = *(const bf16x8*)(gwt1 + (16*w + r16)*128 + ks*32 + q*8);
  #pragma unroll
  for (int ks = 0; ks < 4; ks++)
    af2[ks] = *(const bf16x8*)(gwt2 + (16*w + r16)*128 + ks*32 + q*8);
  float4 b40 = *(const float4*)(gb0 + 16*w + 4*q);
  float4 b41 = *(const float4*)(gb1 + 16*w + 4*q);
  float4 b42 = *(const float4*)(gb2 + 16*w + 4*q);

  // bn1 scale/shift from global accumulators
  if (tid < 64){
    float s = stat1acc[tid], s2 = stat1acc[64 + tid];
    float m = s*(1.f/NNODES), v = s2*(1.f/NNODES) - m*m;
    float sc = rsqrtf(v + 1e-5f)*bn1g[tid];
    bsc[tid] = sc; bsh[tid] = bn1b[tid] - m*sc;
  }
  if (tid < 256) st2[tid] = 0.f;
  {
    unsigned* td = (unsigned*)ewl;
    for (int idx = tid; idx < 64*EW_STR/2; idx += 512) td[idx] = 0;
  }
  {
    unsigned* hsd = (unsigned*)hs;
    for (int idx = tid; idx < 3*(HS_STR/2); idx += 512){
      int rr = 61 + idx/(HS_STR/2), cc = idx%(HS_STR/2);
      hsd[rr*(HS_STR/2) + cc] = 0;
    }
  }
  __syncthreads();

  // edge tanh -> dense LDS matrix + transposed global output
  {
    float v0 = eww[0], v1 = eww[1], v2 = eww[2], bb = ewb[0];
    const float* efg = ef + (size_t)g*EPG*3;
    for (int idx = tid; idx < EPG; idx += 512){
      const float* p = efg + idx*3;
      float v = tanhf(p[0]*v0 + p[1]*v1 + p[2]*v2 + bb);
      int s = idx/60, r = idx - s*60;
      int d = r + (r >= s ? 1 : 0);
      ewl[d*EW_STR + s] = f2bf(v);
      out2[(size_t)idx*128 + g] = v;
    }
  }
  // bn1-normalized node features -> hs
  {
    unsigned* hsd = (unsigned*)hs;
    for (int idx = tid; idx < 61*32; idx += 512){
      int i = idx >> 5, kw = idx & 31;
      float2 hv = *(const float2*)(h0 + ((size_t)g*61 + i)*64 + kw*2);
      int k0 = kw*2;
      float a = hv.x*bsc[k0] + bsh[k0];
      float b = hv.y*bsc[k0+1] + bsh[k0+1];
      hsd[i*(HS_STR/2) + kw] = (unsigned)f2bf(a) | ((unsigned)f2bf(b) << 16);
    }
  }
  __syncthreads();
  bf16x8 ewf[2];
  #pragma unroll
  for (int ks = 0; ks < 2; ks++)
    ewf[ks] = *(const bf16x8*)(ewl + (16*dt + r16)*EW_STR + ks*32 + q*8);

  // layer 0
  #pragma unroll
  for (int nt = 0; nt < 4; nt++){
    float4v acc = {b40.x, b40.y, b40.z, b40.w};
    #pragma unroll
    for (int ks = 0; ks < 2; ks++){
      bf16x8 bv = *(const bf16x8*)(hs + (nt*16 + r16)*HS_STR + ks*32 + q*8);
      acc = __builtin_amdgcn_mfma_f32_16x16x32_bf16(af0[ks], bv, acc, 0, 0, 0);
    }
    #pragma unroll
    for (int r = 0; r < 4; r++)
      hwT[(16*w + 4*q + r)*HWT_STR + nt*16 + r16] = f2bf(acc[r]);
  }
  __syncthreads();
  #pragma unroll
  for (int nt = 0; nt < 4; nt++){
    int j = (jh*4 + nt)*16;
    float4v acc = {0.f,0.f,0.f,0.f};
    #pragma unroll
    for (int ks = 0; ks < 2; ks++){
      bf16x8 bv = *(const bf16x8*)(hwT + (j + r16)*HWT_STR + ks*32 + q*8);
      acc = __builtin_amdgcn_mfma_f32_16x16x32_bf16(ewf[ks], bv, acc, 0, 0, 0);
    }
    #pragma unroll
    for (int r = 0; r < 4; r++){
      int d = 16*dt + 4*q + r;
      hs[d*HS_STR + j + r16] = f2bf(fmaxf(acc[r], 0.f));
    }
  }
  __syncthreads();

  // layer 1
  #pragma unroll
  for (int nt = 0; nt < 4; nt++){
    float4v acc = {b41.x, b41.y, b41.z, b41.w};
    #pragma unroll
    for (int ks = 0; ks < 4; ks++){
      bf16x8 bv = *(const bf16x8*)(hs + (nt*16 + r16)*HS_STR + ks*32 + q*8);
      acc = __builtin_amdgcn_mfma_f32_16x16x32_bf16(af1[ks], bv, acc, 0, 0, 0);
    }
    #pragma unroll
    for (int r = 0; r < 4; r++)
      hwT[(16*w + 4*q + r)*HWT_STR + nt*16 + r16] = f2bf(acc[r]);
  }
  __syncthreads();
  #pragma unroll
  for (int nt = 0; nt < 4; nt++){
    int j = (jh*4 + nt)*16;
    float4v acc = {0.f,0.f,0.f,0.f};
    #pragma unroll
    for (int ks = 0; ks < 2; ks++){
      bf16x8 bv = *(const bf16x8*)(hwT + (j + r16)*HWT_STR + ks*32 + q*8);
      acc = __builtin_amdgcn_mfma_f32_16x16x32_bf16(ewf[ks], bv, acc, 0, 0, 0);
    }
    #pragma unroll
    for (int r = 0; r < 4; r++){
      int d = 16*dt + 4*q + r;
      hs[d*HS_STR + j + r16] = f2bf(fmaxf(acc[r], 0.f));
    }
  }
  __syncthreads();

  // layer 2 (+ bn2 stats tail)
  #pragma unroll
  for (int nt = 0; nt < 4; nt++){
    float4v acc = {b42.x, b42.y, b42.z, b42.w};
    #pragma unroll
    for (int ks = 0; ks < 4; ks++){
      bf16x8 bv = *(const bf16x8*)(hs + (nt*16 + r16)*HS_STR + ks*32 + q*8);
      acc = __builtin_amdgcn_mfma_f32_16x16x32_bf16(af2[ks], bv, acc, 0, 0, 0);
    }
    #pragma unroll
    for (int r = 0; r < 4; r++)
      hwT[(16*w + 4*q + r)*HWT_STR + nt*16 + r16] = f2bf(acc[r]);
  }
  __syncthreads();
  #pragma unroll
  for (int nt = 0; nt < 4; nt++){
    int j = (jh*4 + nt)*16;
    float4v acc = {0.f,0.f,0.f,0.f};
    #pragma unroll
    for (int ks = 0; ks < 2; ks++){
      bf16x8 bv = *(const bf16x8*)(hwT + (j + r16)*HWT_STR + ks*32 + q*8);
      acc = __builtin_amdgcn_mfma_f32_16x16x32_bf16(ewf[ks], bv, acc, 0, 0, 0);
    }
    float cs = 0.f, cq = 0.f;
    #pragma unroll
    for (int r = 0; r < 4; r++){
      int d = 16*dt + 4*q + r;
      if (d < 61){
        float v = acc[r];
        hB[((size_t)g*61 + d)*128 + j + r16] = f2bf(v);
        cs += v; cq += v*v;
      }
    }
    int col = j + r16;
    atomicAdd(&st2[col], cs);
    atomicAdd(&st2[128 + col], cq);
  }
  __syncthreads();
  if (tid < 256) atomicAdd(&stat2acc[tid], st2[tid]);
}

// ---------------- lin0 via MFMA, atomic split-K into y0pre ------------------
#define AS_STR 136
__global__ __launch_bounds__(256) void k_mlp0(const u16* __restrict__ hB,
    const float* __restrict__ stat2acc,
    const float* __restrict__ bn2g, const float* __restrict__ bn2b,
    const u16* __restrict__ lw0t, float* __restrict__ y0pre){
  int bi = blockIdx.x; int i = bi >> 2, sub = bi & 3;
  int oh = sub & 1, gh = sub >> 1;
  int tid = threadIdx.x, w = tid >> 6, lane = tid & 63, q = lane >> 4, r16 = lane & 15;
  __shared__ u16 As[64*AS_STR];
  __shared__ float sc2[128], sh2[128];
  if (tid < 128){
    float s = stat2acc[tid], s2 = stat2acc[128 + tid];
    float m = s*(1.f/NNODES), v = s2*(1.f/NNODES) - m*m;
    float sc = rsqrtf(v + 1e-5f)*bn2g[tid];
    sc2[tid] = sc; sh2[tid] = bn2b[tid] - m*sc;
  }
  __syncthreads();
  {
    const unsigned* hbd = (const unsigned*)hB;
    unsigned* asd = (unsigned*)As;
    for (int idx = tid; idx < 4096; idx += 256){
      int gg = gh*64 + (idx >> 6), kw = idx & 63;
      unsigned pv = hbd[((size_t)gg*61 + i)*64 + kw];
      int k0 = kw*2;
      float a = bf2f(pv & 0xffffu)*sc2[k0] + sh2[k0];
      float b = bf2f(pv >> 16)*sc2[k0+1] + sh2[k0+1];
      asd[(idx >> 6)*(AS_STR/2) + kw] = (unsigned)f2bf(a) | ((unsigned)f2bf(b) << 16);
    }
  }
  __syncthreads();
  const u16* wbase = lw0t + ((size_t)i*128 + oh*64)*128;
  bf16x8 af[4];
  #pragma unroll
  for (int ks = 0; ks < 4; ks++)
    af[ks] = *(const bf16x8*)(As + (16*w + r16)*AS_STR + ks*32 + q*8);
  #pragma unroll
  for (int nt = 0; nt < 4; nt++){
    float4v acc = {0.f,0.f,0.f,0.f};
    #pragma unroll
    for (int ks = 0; ks < 4; ks++){
      bf16x8 bv = *(const bf16x8*)(wbase + (size_t)(nt*16 + r16)*128 + ks*32 + q*8);
      acc = __builtin_amdgcn_mfma_f32_16x16x32_bf16(af[ks], bv, acc, 0, 0, 0);
    }
    #pragma unroll
    for (int r = 0; r < 4; r++){
      int g = gh*64 + 16*w + 4*q + r;
      atomicAdd(&y0pre[(size_t)g*128 + oh*64 + nt*16 + r16], acc[r]);
    }
  }
}

// ---------------- epilogue: bias+relu + lin1 + lin2 + log_softmax -----------
__global__ __launch_bounds__(128) void k_mlp1(const float* __restrict__ y0pre,
    const float* __restrict__ lb0, const float* __restrict__ W1,
    const float* __restrict__ lb1, const float* __restrict__ W2,
    const float* __restrict__ lb2, float* __restrict__ out){
  int g = blockIdx.x, o = threadIdx.x;
  __shared__ float y0[128], y1[128], red[128];
  y0[o] = fmaxf(y0pre[(size_t)g*128 + o] + lb0[o], 0.f);
  __syncthreads();
  float a = lb1[o];
  #pragma unroll 8
  for (int k = 0; k < 128; k++) a += y0[k]*W1[k*128 + o];
  y1[o] = fmaxf(a, 0.f);
  __syncthreads();
  int c = o & 3, kb = o >> 2;
  float a2 = 0.f;
  #pragma unroll
  for (int j = 0; j < 4; j++){
    int k = kb + 32*j;
    a2 += y1[k]*W2[k*4 + c];
  }
  red[o] = a2;
  __syncthreads();
  #pragma unroll
  for (int off = 64; off >= 4; off >>= 1){
    if (o < off) red[o] += red[o + off];
    __syncthreads();
  }
  if (o == 0){
    float v0 = red[0]+lb2[0], v1 = red[1]+lb2[1], v2 = red[2]+lb2[2], v3 = red[3]+lb2[3];
    float m = fmaxf(fmaxf(v0,v1), fmaxf(v2,v3));
    float lse = m + logf(expf(v0-m)+expf(v1-m)+expf(v2-m)+expf(v3-m));
    out[g*4+0]=v0-lse; out[g*4+1]=v1-lse; out[g*4+2]=v2-lse; out[g*4+3]=v3-lse;
  }
}

extern "C" void kernel_launch(void* const* d_in, const int* in_sizes, int n_in,
                              void* d_out, int out_size, void* d_ws, size_t ws_size,
                              hipStream_t stream){
  const float* x    = (const float*)d_in[0];
  const float* ef   = (const float*)d_in[3];
  const float* cw0  = (const float*)d_in[4];
  const float* cb0  = (const float*)d_in[5];
  const float* cw1  = (const float*)d_in[6];
  const float* cb1  = (const float*)d_in[7];
  const float* cw2  = (const float*)d_in[8];
  const float* cb2  = (const float*)d_in[9];
  const float* bn1g = (const float*)d_in[10];
  const float* bn1b = (const float*)d_in[11];
  const float* gw0  = (const float*)d_in[12];
  const float* gb0  = (const float*)d_in[13];
  const float* gw1  = (const float*)d_in[14];
  const float* gb1  = (const float*)d_in[15];
  const float* gw2  = (const float*)d_in[16];
  const float* gb2  = (const float*)d_in[17];
  const float* bn2g = (const float*)d_in[18];
  const float* bn2b = (const float*)d_in[19];
  const float* lw0  = (const float*)d_in[20];
  const float* lb0  = (const float*)d_in[21];
  const float* lw1  = (const float*)d_in[22];
  const float* lb1  = (const float*)d_in[23];
  const float* lw2  = (const float*)d_in[24];
  const float* lb2  = (const float*)d_in[25];
  const float* eww  = (const float*)d_in[26];
  const float* ewb  = (const float*)d_in[27];
  float* out = (float*)d_out;

  float* ws   = (float*)d_ws;
  float* w1s  = ws;               // 10240 f
  float* w2s  = w1s + 10240;      // 6144 f
  float* w0t  = w2s + 6144;       // 448 f
  float* gws0 = w0t + 448;        // 4096 f
  float* gws1 = gws0 + 4096;      // 8192 f
  float* gws2 = gws1 + 8192;      // 8192 f
  float* h0   = gws2 + 8192;      // 499712 f (7808*64 f32)
  float* hBs  = h0 + 499712;      // 499712 f (7808*128 u16)
  float* lw0s = hBs + 499712;     // 499712 f (61*128*128 u16)
  float* accs = lw0s + 499712;    // 16768 f: stat1acc(128) | stat2acc(256) | y0pre(16384)
  // total ~ 6.2 MB

  u16* w1b    = (u16*)w1s;
  u16* w2b    = (u16*)w2s;
  u16* gwt0   = (u16*)gws0;
  u16* gwt1   = (u16*)gws1;
  u16* gwt2   = (u16*)gws2;
  u16* hB     = (u16*)hBs;
  u16* lw0t   = (u16*)lw0s;
  float* stat1acc = accs;
  float* stat2acc = accs + 128;
  float* y0pre    = accs + 384;

  hipMemsetAsync(accs, 0, 16768*sizeof(float), stream);
  k_prep <<<534, 256, 0, stream>>>(cw0, cw1, cw2, gw0, gw1, gw2, lw0,
                                   w0t, w1b, w2b, gwt0, gwt1, gwt2, lw0t);
  k_conv <<<NNODES/4, 256, 0, stream>>>(x, w0t, cb0, w1b, cb1, w2b, cb2, h0, stat1acc);
  k_gnn  <<<NGRAPH, 512, 0, stream>>>(h0, stat1acc, bn1g, bn1b,
                                      gwt0, gb0, gwt1, gb1, gwt2, gb2,
                                      ef, eww, ewb, out + 512, hB, stat2acc);
  k_mlp0 <<<NPGN*4, 256, 0, stream>>>(hB, stat2acc, bn2g, bn2b, lw0t, y0pre);
  k_mlp1 <<<NGRAPH, 128, 0, stream>>>(y0pre, lb0, lw1, lb1, lw2, lb2, out);
}

// Round 12
// 226.425 us; speedup vs baseline: 1.1447x; 1.0640x over previous
//
#include <hip/hip_runtime.h>
#include <math.h>

#define NPGN 61
#define NGRAPH 128
#define NNODES (NPGN*NGRAPH)   // 7808
#define EPG 3660               // 61*60 edges per graph

typedef float float4v __attribute__((ext_vector_type(4)));
typedef short bf16x8 __attribute__((ext_vector_type(8)));
typedef unsigned short u16;

__device__ __forceinline__ u16 f2bf(float v){
  union { float f; unsigned u; } x; x.f = v;
  unsigned r = (x.u + 0x7FFFu + ((x.u >> 16) & 1u)) >> 16;
  return (u16)r;
}
__device__ __forceinline__ float bf2f(unsigned u){
  union { unsigned u; float f; } x; x.u = u << 16;
  return x.f;
}

// ---------------- fused prep: weight re-layouts + lw0 transpose -------------
__global__ __launch_bounds__(256) void k_prep(const float* __restrict__ w0,
    const float* __restrict__ w1, const float* __restrict__ w2,
    const float* __restrict__ gw0, const float* __restrict__ gw1, const float* __restrict__ gw2,
    const float* __restrict__ lw0,
    float* __restrict__ w0t, u16* __restrict__ w1b, u16* __restrict__ w2b,
    u16* __restrict__ gwt0, u16* __restrict__ gwt1, u16* __restrict__ gwt2,
    u16* __restrict__ lw0t){
  __shared__ __align__(16) u16 tile[32*132];
  int b = blockIdx.x, tid = threadIdx.x;
  if (b < 290){
    int idx = b*256 + tid;
    if (idx < 20480){
      int f = idx / 320, r = idx - f*320;
      int kk = r >> 6, c = r & 63;
      w1b[idx] = f2bf(w1[f*320 + c*5 + kk]);
    } else if (idx < 32768){
      int j = idx - 20480; w2b[j] = f2bf(w2[j]);
    } else if (idx < 40960){
      int j = idx - 32768; int jj = j >> 6, k = j & 63; gwt0[j] = f2bf(gw0[k*128 + jj]);
    } else if (idx < 57344){
      int j = idx - 40960; int jj = j >> 7, k = j & 127; gwt1[j] = f2bf(gw1[k*128 + jj]);
    } else if (idx < 73728){
      int j = idx - 57344; int jj = j >> 7, k = j & 127; gwt2[j] = f2bf(gw2[k*128 + jj]);
    } else if (idx < 74176){
      int j = idx - 73728; int k = j >> 6, f = j & 63; w0t[j] = w0[f*7 + k];
    }
  } else {
    int bb = b - 290;
    int i = bb >> 2, oq = bb & 3;      // o-chunk of 32
    for (int idx = tid; idx < 4096; idx += 256){
      int k = idx >> 5, ol = idx & 31;
      tile[ol*132 + k] = f2bf(lw0[((size_t)i*128 + k)*128 + oq*32 + ol]);
    }
    __syncthreads();
    unsigned* dst = (unsigned*)lw0t;
    for (int idx = tid; idx < 2048; idx += 256){
      int ol = idx >> 6, kw = idx & 63;
      unsigned v = (unsigned)tile[ol*132 + 2*kw] | ((unsigned)tile[ol*132 + 2*kw + 1] << 16);
      dst[((size_t)i*128 + oq*32 + ol)*64 + kw] = v;
    }
  }
}

// ---------------- fused conv stack + bucketed bn1-stats tail ----------------
// 4 independent waves/block, 1 node/wave; conv0 scalar-VALU, conv1/conv2 MFMA
#define A0T_STR 72   // u16 units (144 B)
#define C1_STR 40    // u16 units (80 B)
__global__ __launch_bounds__(256) void k_conv(const float* __restrict__ x,
    const float* __restrict__ w0t, const float* __restrict__ b0,
    const u16* __restrict__ w1b, const float* __restrict__ b1,
    const u16* __restrict__ w2b, const float* __restrict__ b2,
    float* __restrict__ h0, float* __restrict__ stat1p){
  int w = threadIdx.x >> 6, lane = threadIdx.x & 63;
  int tid = threadIdx.x;
  int n = blockIdx.x*4 + w;
  __shared__ __align__(16) u16 a0t_s[4][36*A0T_STR];  // 5184 B/wave; c1 overlays
  __shared__ __align__(16) u16 a1k_s[4][208];         // conv2 input vector
  __shared__ float hstat[4][128];
  u16* a0t = a0t_s[w];
  u16* a1k = a1k_s[w];

  // wave-uniform x row -> scalar loads
  const float* xrow = x + (size_t)__builtin_amdgcn_readfirstlane(n)*160;

  float w0r[7];
  #pragma unroll
  for (int k = 0; k < 7; k++) w0r[k] = w0t[k*64 + lane];
  float b0f = b0[lane];
  #pragma unroll
  for (int rp = 0; rp < 36; rp++)
    if (rp < 2 || rp >= 24) a0t[rp*A0T_STR + lane] = 0;

  // conv0 (K=7) + relu + maxpool7 : 160 -> 154 -> 22 ; lane = channel
  #pragma unroll 2
  for (int qp = 0; qp < 11; qp++){
    float win[20];
    #pragma unroll
    for (int j = 0; j < 20; j++) win[j] = xrow[14*qp + j];
    float m0, m1;
    #pragma unroll
    for (int r = 0; r < 7; r++){
      float s = w0r[0]*win[r];
      #pragma unroll
      for (int k = 1; k < 7; k++) s += w0r[k]*win[r+k];
      m0 = r ? fmaxf(m0, s) : s;
    }
    #pragma unroll
    for (int r = 7; r < 14; r++){
      float s = w0r[0]*win[r];
      #pragma unroll
      for (int k = 1; k < 7; k++) s += w0r[k]*win[r+k];
      m1 = (r > 7) ? fmaxf(m1, s) : s;
    }
    a0t[(2 + 2*qp)*A0T_STR + lane] = f2bf(fmaxf(m0 + b0f, 0.f));
    a0t[(3 + 2*qp)*A0T_STR + lane] = f2bf(fmaxf(m1 + b0f, 0.f));
  }

  // conv1 MFMA: C[64f][22p] = W[64f][320] * B[320][22p], k = kk*64 + c
  int q = lane >> 4, r16 = lane & 15;
  float4v acc[4][2];
  #pragma unroll
  for (int mt = 0; mt < 4; mt++)
    #pragma unroll
    for (int nt = 0; nt < 2; nt++)
      acc[mt][nt] = (float4v){0.f,0.f,0.f,0.f};
  #pragma unroll 1
  for (int ks = 0; ks < 10; ks++){
    int kk = ks >> 1;
    int cbase = (ks & 1)*32 + q*8;
    bf16x8 af[4];
    #pragma unroll
    for (int mt = 0; mt < 4; mt++)
      af[mt] = *(const bf16x8*)(w1b + (16*mt + r16)*320 + ks*32 + q*8);
    bf16x8 bv[2];
    #pragma unroll
    for (int nt = 0; nt < 2; nt++)
      bv[nt] = *(const bf16x8*)(a0t + (r16 + 16*nt + kk)*A0T_STR + cbase);
    #pragma unroll
    for (int mt = 0; mt < 4; mt++)
      #pragma unroll
      for (int nt = 0; nt < 2; nt++)
        acc[mt][nt] = __builtin_amdgcn_mfma_f32_16x16x32_bf16(af[mt], bv[nt], acc[mt][nt], 0, 0, 0);
  }

  // bias + relu -> c1 (bf16, overlays a0t; same-wave DS ops in-order)
  u16* c1 = a0t;
  #pragma unroll
  for (int mt = 0; mt < 4; mt++){
    float4 bb = *(const float4*)(b1 + 16*mt + 4*q);
    #pragma unroll
    for (int reg = 0; reg < 4; reg++){
      int m = 16*mt + q*4 + reg;
      float bv_ = ((const float*)&bb)[reg];
      c1[m*C1_STR + r16] = f2bf(fmaxf(acc[mt][0][reg] + bv_, 0.f));
      if (r16 <= 4)
        c1[m*C1_STR + 16 + r16] = f2bf(fmaxf(acc[mt][1][reg] + bv_, 0.f));
    }
  }

  // maxpool7 (21 -> 3), lane = channel; contiguous k-vector a1k[c*3+t]
  {
    bf16x8 f0 = *(const bf16x8*)(c1 + lane*C1_STR);
    bf16x8 f1 = *(const bf16x8*)(c1 + lane*C1_STR + 8);
    bf16x8 f2 = *(const bf16x8*)(c1 + lane*C1_STR + 16);
    float v[24];
    #pragma unroll
    for (int j = 0; j < 8; j++){
      v[j]    = bf2f((u16)f0[j]);
      v[8+j]  = bf2f((u16)f1[j]);
      v[16+j] = bf2f((u16)f2[j]);
    }
    #pragma unroll
    for (int t = 0; t < 3; t++){
      float m = v[t*7];
      #pragma unroll
      for (int r = 1; r < 7; r++) m = fmaxf(m, v[t*7+r]);
      a1k[lane*3 + t] = f2bf(m);
    }
  }

  // conv2 via MFMA: C[f][*] = W2[64f][192k] * a1[192k]
  float4v acc2[4];
  #pragma unroll
  for (int mt = 0; mt < 4; mt++) acc2[mt] = (float4v){0.f,0.f,0.f,0.f};
  #pragma unroll
  for (int ks = 0; ks < 6; ks++){
    bf16x8 bs = *(const bf16x8*)(a1k + ks*32 + q*8);
    #pragma unroll
    for (int mt = 0; mt < 4; mt++){
      bf16x8 af = *(const bf16x8*)(w2b + (16*mt + r16)*192 + ks*32 + q*8);
      acc2[mt] = __builtin_amdgcn_mfma_f32_16x16x32_bf16(af, bs, acc2[mt], 0, 0, 0);
    }
  }
  if (r16 == 0){
    #pragma unroll
    for (int mt = 0; mt < 4; mt++)
      #pragma unroll
      for (int reg = 0; reg < 4; reg++){
        int f = 16*mt + 4*q + reg;
        float v = acc2[mt][reg] + b2[f];
        h0[(size_t)n*64 + f] = v;
        hstat[w][f] = v;
        hstat[w][64 + f] = v*v;
      }
  }
  __syncthreads();
  // per-block bn1 partial -> 32-way bucketed atomic accumulators (low contention)
  if (tid < 128){
    float a = hstat[0][tid] + hstat[1][tid] + hstat[2][tid] + hstat[3][tid];
    atomicAdd(&stat1p[(blockIdx.x & 31)*128 + tid], a);
  }
}

// ---------------- fused GNN: edge-tanh head + 3 MFMA layers + bn2 partials --
#define EW_STR 72
#define HS_STR 136
#define HWT_STR 72
__global__ __launch_bounds__(512) void k_gnn(const float* __restrict__ h0,
    const float* __restrict__ stat1p,
    const float* __restrict__ bn1g, const float* __restrict__ bn1b,
    const u16* __restrict__ gwt0, const float* __restrict__ gb0,
    const u16* __restrict__ gwt1, const float* __restrict__ gb1,
    const u16* __restrict__ gwt2, const float* __restrict__ gb2,
    const float* __restrict__ ef, const float* __restrict__ eww,
    const float* __restrict__ ewb, float* __restrict__ out2,
    u16* __restrict__ hB, float* __restrict__ stat2p){
  int g = blockIdx.x, tid = threadIdx.x;
  int w = tid >> 6, lane = tid & 63, q = lane >> 4, r16 = lane & 15;
  int dt = w & 3, jh = w >> 2;
  __shared__ u16 hs[64*HS_STR];
  __shared__ u16 hwT[128*HWT_STR];
  __shared__ u16 ewl[64*EW_STR];
  __shared__ float bsc[64], bsh[64];
  __shared__ float st2[256];

  bf16x8 af0[2], af1[4], af2[4];
  #pragma unroll
  for (int ks = 0; ks < 2; ks++)
    af0[ks] = *(const bf16x8*)(gwt0 + (16*w + r16)*64 + ks*32 + q*8);
  #pragma unroll
  for (int ks = 0; ks < 4; ks++)
    af1[ks] = *(const bf16x8*)(gwt1 + (16*w + r16)*128 + ks*32 + q*8);
  #pragma unroll
  for (int ks = 0; ks < 4; ks++)
    af2[ks] = *(const bf16x8*)(gwt2 + (16*w + r16)*128 + ks*32 + q*8);
  float4 b40 = *(const float4*)(gb0 + 16*w + 4*q);
  float4 b41 = *(const float4*)(gb1 + 16*w + 4*q);
  float4 b42 = *(const float4*)(gb2 + 16*w + 4*q);

  // bn1 scale/shift from bucketed accumulators
  if (tid < 64){
    float s = 0.f, s2 = 0.f;
    #pragma unroll
    for (int r = 0; r < 32; r++){
      s  += stat1p[r*128 + tid];
      s2 += stat1p[r*128 + 64 + tid];
    }
    float m = s*(1.f/NNODES), v = s2*(1.f/NNODES) - m*m;
    float sc = rsqrtf(v + 1e-5f)*bn1g[tid];
    bsc[tid] = sc; bsh[tid] = bn1b[tid] - m*sc;
  }
  if (tid < 256) st2[tid] = 0.f;
  {
    unsigned* td = (unsigned*)ewl;
    for (int idx = tid; idx < 64*EW_STR/2; idx += 512) td[idx] = 0;
  }
  {
    unsigned* hsd = (unsigned*)hs;
    for (int idx = tid; idx < 3*(HS_STR/2); idx += 512){
      int rr = 61 + idx/(HS_STR/2), cc = idx%(HS_STR/2);
      hsd[rr*(HS_STR/2) + cc] = 0;
    }
  }
  __syncthreads();

  // edge tanh -> dense LDS matrix + transposed global output
  {
    float v0 = eww[0], v1 = eww[1], v2 = eww[2], bb = ewb[0];
    const float* efg = ef + (size_t)g*EPG*3;
    for (int idx = tid; idx < EPG; idx += 512){
      const float* p = efg + idx*3;
      float v = tanhf(p[0]*v0 + p[1]*v1 + p[2]*v2 + bb);
      int s = idx/60, r = idx - s*60;
      int d = r + (r >= s ? 1 : 0);
      ewl[d*EW_STR + s] = f2bf(v);
      out2[(size_t)idx*128 + g] = v;
    }
  }
  // bn1-normalized node features -> hs
  {
    unsigned* hsd = (unsigned*)hs;
    for (int idx = tid; idx < 61*32; idx += 512){
      int i = idx >> 5, kw = idx & 31;
      float2 hv = *(const float2*)(h0 + ((size_t)g*61 + i)*64 + kw*2);
      int k0 = kw*2;
      float a = hv.x*bsc[k0] + bsh[k0];
      float b = hv.y*bsc[k0+1] + bsh[k0+1];
      hsd[i*(HS_STR/2) + kw] = (unsigned)f2bf(a) | ((unsigned)f2bf(b) << 16);
    }
  }
  __syncthreads();
  bf16x8 ewf[2];
  #pragma unroll
  for (int ks = 0; ks < 2; ks++)
    ewf[ks] = *(const bf16x8*)(ewl + (16*dt + r16)*EW_STR + ks*32 + q*8);

  // layer 0
  #pragma unroll
  for (int nt = 0; nt < 4; nt++){
    float4v acc = {b40.x, b40.y, b40.z, b40.w};
    #pragma unroll
    for (int ks = 0; ks < 2; ks++){
      bf16x8 bv = *(const bf16x8*)(hs + (nt*16 + r16)*HS_STR + ks*32 + q*8);
      acc = __builtin_amdgcn_mfma_f32_16x16x32_bf16(af0[ks], bv, acc, 0, 0, 0);
    }
    #pragma unroll
    for (int r = 0; r < 4; r++)
      hwT[(16*w + 4*q + r)*HWT_STR + nt*16 + r16] = f2bf(acc[r]);
  }
  __syncthreads();
  #pragma unroll
  for (int nt = 0; nt < 4; nt++){
    int j = (jh*4 + nt)*16;
    float4v acc = {0.f,0.f,0.f,0.f};
    #pragma unroll
    for (int ks = 0; ks < 2; ks++){
      bf16x8 bv = *(const bf16x8*)(hwT + (j + r16)*HWT_STR + ks*32 + q*8);
      acc = __builtin_amdgcn_mfma_f32_16x16x32_bf16(ewf[ks], bv, acc, 0, 0, 0);
    }
    #pragma unroll
    for (int r = 0; r < 4; r++){
      int d = 16*dt + 4*q + r;
      hs[d*HS_STR + j + r16] = f2bf(fmaxf(acc[r], 0.f));
    }
  }
  __syncthreads();

  // layer 1
  #pragma unroll
  for (int nt = 0; nt < 4; nt++){
    float4v acc = {b41.x, b41.y, b41.z, b41.w};
    #pragma unroll
    for (int ks = 0; ks < 4; ks++){
      bf16x8 bv = *(const bf16x8*)(hs + (nt*16 + r16)*HS_STR + ks*32 + q*8);
      acc = __builtin_amdgcn_mfma_f32_16x16x32_bf16(af1[ks], bv, acc, 0, 0, 0);
    }
    #pragma unroll
    for (int r = 0; r < 4; r++)
      hwT[(16*w + 4*q + r)*HWT_STR + nt*16 + r16] = f2bf(acc[r]);
  }
  __syncthreads();
  #pragma unroll
  for (int nt = 0; nt < 4; nt++){
    int j = (jh*4 + nt)*16;
    float4v acc = {0.f,0.f,0.f,0.f};
    #pragma unroll
    for (int ks = 0; ks < 2; ks++){
      bf16x8 bv = *(const bf16x8*)(hwT + (j + r16)*HWT_STR + ks*32 + q*8);
      acc = __builtin_amdgcn_mfma_f32_16x16x32_bf16(ewf[ks], bv, acc, 0, 0, 0);
    }
    #pragma unroll
    for (int r = 0; r < 4; r++){
      int d = 16*dt + 4*q + r;
      hs[d*HS_STR + j + r16] = f2bf(fmaxf(acc[r], 0.f));
    }
  }
  __syncthreads();

  // layer 2 (+ bn2 partial tail, atomic-free)
  #pragma unroll
  for (int nt = 0; nt < 4; nt++){
    float4v acc = {b42.x, b42.y, b42.z, b42.w};
    #pragma unroll
    for (int ks = 0; ks < 4; ks++){
      bf16x8 bv = *(const bf16x8*)(hs + (nt*16 + r16)*HS_STR + ks*32 + q*8);
      acc = __builtin_amdgcn_mfma_f32_16x16x32_bf16(af2[ks], bv, acc, 0, 0, 0);
    }
    #pragma unroll
    for (int r = 0; r < 4; r++)
      hwT[(16*w + 4*q + r)*HWT_STR + nt*16 + r16] = f2bf(acc[r]);
  }
  __syncthreads();
  #pragma unroll
  for (int nt = 0; nt < 4; nt++){
    int j = (jh*4 + nt)*16;
    float4v acc = {0.f,0.f,0.f,0.f};
    #pragma unroll
    for (int ks = 0; ks < 2; ks++){
      bf16x8 bv = *(const bf16x8*)(hwT + (j + r16)*HWT_STR + ks*32 + q*8);
      acc = __builtin_amdgcn_mfma_f32_16x16x32_bf16(ewf[ks], bv, acc, 0, 0, 0);
    }
    float cs = 0.f, cq = 0.f;
    #pragma unroll
    for (int r = 0; r < 4; r++){
      int d = 16*dt + 4*q + r;
      if (d < 61){
        float v = acc[r];
        hB[((size_t)g*61 + d)*128 + j + r16] = f2bf(v);
        cs += v; cq += v*v;
      }
    }
    int col = j + r16;
    atomicAdd(&st2[col], cs);       // LDS atomics (block-local, cheap)
    atomicAdd(&st2[128 + col], cq);
  }
  __syncthreads();
  if (tid < 256) stat2p[(size_t)tid*128 + g] = st2[tid];   // private column, no atomics
}

// ---------------- lin0 via MFMA, atomic split-K into y0pre ------------------
#define AS_STR 136
__global__ __launch_bounds__(256) void k_mlp0(const u16* __restrict__ hB,
    const float* __restrict__ stat2p,
    const float* __restrict__ bn2g, const float* __restrict__ bn2b,
    const u16* __restrict__ lw0t, float* __restrict__ y0pre){
  int bi = blockIdx.x; int i = bi >> 2, sub = bi & 3;
  int oh = sub & 1, gh = sub >> 1;
  int tid = threadIdx.x, w = tid >> 6, lane = tid & 63, q = lane >> 4, r16 = lane & 15;
  __shared__ u16 As[64*AS_STR];
  __shared__ float sc2[128], sh2[128];
  if (tid < 128){
    float4v sa = {0,0,0,0}, sb = {0,0,0,0};
    #pragma unroll
    for (int r = 0; r < 32; r++){
      sa += *(const float4v*)(stat2p + (size_t)tid*128 + r*4);
      sb += *(const float4v*)(stat2p + (size_t)(128 + tid)*128 + r*4);
    }
    float s = sa[0]+sa[1]+sa[2]+sa[3], s2 = sb[0]+sb[1]+sb[2]+sb[3];
    float m = s*(1.f/NNODES), v = s2*(1.f/NNODES) - m*m;
    float sc = rsqrtf(v + 1e-5f)*bn2g[tid];
    sc2[tid] = sc; sh2[tid] = bn2b[tid] - m*sc;
  }
  __syncthreads();
  {
    const unsigned* hbd = (const unsigned*)hB;
    unsigned* asd = (unsigned*)As;
    for (int idx = tid; idx < 4096; idx += 256){
      int gg = gh*64 + (idx >> 6), kw = idx & 63;
      unsigned pv = hbd[((size_t)gg*61 + i)*64 + kw];
      int k0 = kw*2;
      float a = bf2f(pv & 0xffffu)*sc2[k0] + sh2[k0];
      float b = bf2f(pv >> 16)*sc2[k0+1] + sh2[k0+1];
      asd[(idx >> 6)*(AS_STR/2) + kw] = (unsigned)f2bf(a) | ((unsigned)f2bf(b) << 16);
    }
  }
  __syncthreads();
  const u16* wbase = lw0t + ((size_t)i*128 + oh*64)*128;
  bf16x8 af[4];
  #pragma unroll
  for (int ks = 0; ks < 4; ks++)
    af[ks] = *(const bf16x8*)(As + (16*w + r16)*AS_STR + ks*32 + q*8);
  #pragma unroll
  for (int nt = 0; nt < 4; nt++){
    float4v acc = {0.f,0.f,0.f,0.f};
    #pragma unroll
    for (int ks = 0; ks < 4; ks++){
      bf16x8 bv = *(const bf16x8*)(wbase + (size_t)(nt*16 + r16)*128 + ks*32 + q*8);
      acc = __builtin_amdgcn_mfma_f32_16x16x32_bf16(af[ks], bv, acc, 0, 0, 0);
    }
    #pragma unroll
    for (int r = 0; r < 4; r++){
      int g = gh*64 + 16*w + 4*q + r;
      atomicAdd(&y0pre[(size_t)g*128 + oh*64 + nt*16 + r16], acc[r]);
    }
  }
}

// ---------------- epilogue: bias+relu + lin1 + lin2 + log_softmax -----------
__global__ __launch_bounds__(128) void k_mlp1(const float* __restrict__ y0pre,
    const float* __restrict__ lb0, const float* __restrict__ W1,
    const float* __restrict__ lb1, const float* __restrict__ W2,
    const float* __restrict__ lb2, float* __restrict__ out){
  int g = blockIdx.x, o = threadIdx.x;
  __shared__ float y0[128], y1[128], red[128];
  y0[o] = fmaxf(y0pre[(size_t)g*128 + o] + lb0[o], 0.f);
  __syncthreads();
  float a = lb1[o];
  #pragma unroll 8
  for (int k = 0; k < 128; k++) a += y0[k]*W1[k*128 + o];
  y1[o] = fmaxf(a, 0.f);
  __syncthreads();
  int c = o & 3, kb = o >> 2;
  float a2 = 0.f;
  #pragma unroll
  for (int j = 0; j < 4; j++){
    int k = kb + 32*j;
    a2 += y1[k]*W2[k*4 + c];
  }
  red[o] = a2;
  __syncthreads();
  #pragma unroll
  for (int off = 64; off >= 4; off >>= 1){
    if (o < off) red[o] += red[o + off];
    __syncthreads();
  }
  if (o == 0){
    float v0 = red[0]+lb2[0], v1 = red[1]+lb2[1], v2 = red[2]+lb2[2], v3 = red[3]+lb2[3];
    float m = fmaxf(fmaxf(v0,v1), fmaxf(v2,v3));
    float lse = m + logf(expf(v0-m)+expf(v1-m)+expf(v2-m)+expf(v3-m));
    out[g*4+0]=v0-lse; out[g*4+1]=v1-lse; out[g*4+2]=v2-lse; out[g*4+3]=v3-lse;
  }
}

extern "C" void kernel_launch(void* const* d_in, const int* in_sizes, int n_in,
                              void* d_out, int out_size, void* d_ws, size_t ws_size,
                              hipStream_t stream){
  const float* x    = (const float*)d_in[0];
  const float* ef   = (const float*)d_in[3];
  const float* cw0  = (const float*)d_in[4];
  const float* cb0  = (const float*)d_in[5];
  const float* cw1  = (const float*)d_in[6];
  const float* cb1  = (const float*)d_in[7];
  const float* cw2  = (const float*)d_in[8];
  const float* cb2  = (const float*)d_in[9];
  const float* bn1g = (const float*)d_in[10];
  const float* bn1b = (const float*)d_in[11];
  const float* gw0  = (const float*)d_in[12];
  const float* gb0  = (const float*)d_in[13];
  const float* gw1  = (const float*)d_in[14];
  const float* gb1  = (const float*)d_in[15];
  const float* gw2  = (const float*)d_in[16];
  const float* gb2  = (const float*)d_in[17];
  const float* bn2g = (const float*)d_in[18];
  const float* bn2b = (const float*)d_in[19];
  const float* lw0  = (const float*)d_in[20];
  const float* lb0  = (const float*)d_in[21];
  const float* lw1  = (const float*)d_in[22];
  const float* lb1  = (const float*)d_in[23];
  const float* lw2  = (const float*)d_in[24];
  const float* lb2  = (const float*)d_in[25];
  const float* eww  = (const float*)d_in[26];
  const float* ewb  = (const float*)d_in[27];
  float* out = (float*)d_out;

  float* ws   = (float*)d_ws;
  float* w1s  = ws;               // 10240 f
  float* w2s  = w1s + 10240;      // 6144 f
  float* w0t  = w2s + 6144;       // 448 f
  float* gws0 = w0t + 448;        // 4096 f
  float* gws1 = gws0 + 4096;      // 8192 f
  float* gws2 = gws1 + 8192;      // 8192 f
  float* h0   = gws2 + 8192;      // 499712 f (7808*64 f32)
  float* hBs  = h0 + 499712;      // 499712 f (7808*128 u16)
  float* lw0s = hBs + 499712;     // 499712 f (61*128*128 u16)
  float* accs = lw0s + 499712;    // stat1p(4096) | y0pre(16384) | stat2p(32768)
  // total ~ 6.3 MB

  u16* w1b    = (u16*)w1s;
  u16* w2b    = (u16*)w2s;
  u16* gwt0   = (u16*)gws0;
  u16* gwt1   = (u16*)gws1;
  u16* gwt2   = (u16*)gws2;
  u16* hB     = (u16*)hBs;
  u16* lw0t   = (u16*)lw0s;
  float* stat1p = accs;           // 32 buckets x 128
  float* y0pre  = accs + 4096;    // 128 x 128
  float* stat2p = accs + 20480;   // 256 cols x 128 graphs

  hipMemsetAsync(accs, 0, 20480*sizeof(float), stream);   // stat1p + y0pre
  k_prep <<<534, 256, 0, stream>>>(cw0, cw1, cw2, gw0, gw1, gw2, lw0,
                                   w0t, w1b, w2b, gwt0, gwt1, gwt2, lw0t);
  k_conv <<<NNODES/4, 256, 0, stream>>>(x, w0t, cb0, w1b, cb1, w2b, cb2, h0, stat1p);
  k_gnn  <<<NGRAPH, 512, 0, stream>>>(h0, stat1p, bn1g, bn1b,
                                      gwt0, gb0, gwt1, gb1, gwt2, gb2,
                                      ef, eww, ewb, out + 512, hB, stat2p);
  k_mlp0 <<<NPGN*4, 256, 0, stream>>>(hB, stat2p, bn2g, bn2b, lw0t, y0pre);
  k_mlp1 <<<NGRAPH, 128, 0, stream>>>(y0pre, lb0, lw1, lb1, lw2, lb2, out);
}